// Round 13
// baseline (604.668 us; speedup 1.0000x reference)
//
#include <hip/hip_runtime.h>

#define EPSF 1e-8f

constexpr int NB = 64;   // batch
constexpr int NO = 64;   // out capsules
constexpr int NI = 1152; // in capsules
constexpr int ND = 16;   // pose dims

constexpr int RSTRIDE = 260;            // 256 floats + 4 pad (16B-aligned rows)
constexpr int BUFSZ   = 64 * RSTRIDE;   // one W-tile: 64 o-rows (66,560 B)

typedef float v2f __attribute__((ext_vector_type(2)));

// fp32 row loader ------------------------------------------------------------
__device__ __forceinline__ void loadrow16f(const float* __restrict__ base,
                                           size_t elem, float* f){
  const float4* p = (const float4*)(base + elem);
  float4 x0=p[0], x1=p[1], x2=p[2], x3=p[3];
  f[0]=x0.x; f[1]=x0.y; f[2]=x0.z; f[3]=x0.w;
  f[4]=x1.x; f[5]=x1.y; f[6]=x1.z; f[7]=x1.w;
  f[8]=x2.x; f[9]=x2.y; f[10]=x2.z; f[11]=x2.w;
  f[12]=x3.x; f[13]=x3.y; f[14]=x3.z; f[15]=x3.w;
}

// async global->LDS, 16 B per lane; lds dst is wave-uniform base + lane*16
__device__ __forceinline__ void gl_lds16(const float* g, float* l){
  __builtin_amdgcn_global_load_lds(
      (const __attribute__((address_space(1))) unsigned int*)g,
      (__attribute__((address_space(3))) unsigned int*)l,
      16, 0, 0);
}

// ---------------- heavy kernel --------------------------------------------
// grid 1-D: bid = bg*CH + c (CH%8==0 -> same-c blocks share bid%8 -> same XCD).
// Block = NW waves (NW=16: 1024 thr => 16 waves = 4/SIMD resident in ONE
// block). Wave w owns batches b0=bg*2NW+2w, b1=b0+1 packed into float2 lanes.
// Per i: W[:,i,:,:] (64KB) DMA'd to LDS rows [o][256] stride 260 (double-
// buffered); lane=o reads its row via ds_read_b128 (conflict-free); V,
// softmax (wave shuffle over o), moments in registers.
// LAUNCH-BOUNDS SEMANTICS (measured R9-R12): 2nd arg = min WORKGROUPS/CU
// (CUDA-style). VGPR cap = 512 / (arg * waves_per_block / 4).
//   (512,2)->128ok  (512,4)->64 SPILL  (1024,4)->64 SPILL  (1024,1)->128.
// NEVER let the cap fall below 128 for this body (~200 live floats).
template<int NW, int MINB, bool ESTEP>
__global__ __launch_bounds__(NW*64, MINB) void k_heavy(
    const float* __restrict__ u, const float* __restrict__ W,
    const float* __restrict__ bias,
    const float* __restrict__ mean0, const float* __restrict__ i2v0,
    const float* __restrict__ c0,
    float* __restrict__ S1p, float* __restrict__ S2p, float* __restrict__ Wsp,
    const int CH)
{
  const int CI = NI / CH;
  constexpr int ROWS = 64 / NW;
  const int bid = blockIdx.x;
  const int bg = bid / CH, c = bid % CH;
  const int t = threadIdx.x, lane = t & 63, w = t >> 6;
  const int b0 = bg*(2*NW) + 2*w, b1 = b0 + 1;
  const int i0 = c*CI;

  __shared__ float buf[2*BUFSZ];   // 133,120 B double buffer

  // per-lane (=o) constants
  float bs[16]; loadrow16f(bias, (size_t)lane*ND, bs);
  v2f mr[16], ir[16]; v2f c01 = {0.f, 0.f};
  if (ESTEP){
    const size_t m0 = ((size_t)b0*NO + lane)*ND;
    const size_t m1 = ((size_t)b1*NO + lane)*ND;
    #pragma unroll
    for (int e=0;e<16;++e){
      mr[e] = v2f{mean0[m0+e], mean0[m1+e]};
      ir[e] = v2f{i2v0[m0+e], i2v0[m1+e]};
    }
    c01 = v2f{c0[(size_t)b0*NO + lane], c0[(size_t)b1*NO + lane]};
  }

  v2f S1[16], S2[16]; v2f wsum = {0.f, 0.f};
  #pragma unroll
  for (int e=0;e<16;++e){ S1[e]=v2f{0.f,0.f}; S2[e]=v2f{0.f,0.f}; }

  // stage W tile for column i into buffer p: wave w covers ROWS o-rows
  auto stage = [&](int p, int i){
    const float* gbase = W + (size_t)i*256 + (size_t)lane*4;
    float* lbase = &buf[p*BUFSZ];
    #pragma unroll
    for (int r=0;r<ROWS;++r){
      const int o = w*ROWS + r;
      gl_lds16(gbase + (size_t)o*NI*256, lbase + o*RSTRIDE);
    }
  };

  int p = 0;
  stage(0, i0);

  for (int ii=0; ii<CI; ++ii){
    const int i = i0 + ii;
    __syncthreads();                  // drains tile-p DMA; gates buffer reuse
    if (ii+1 < CI) stage(p^1, i+1);   // async, overlaps compute below

    // u rows for both batches, interleaved into float2 (broadcast loads)
    v2f u01[16];
    {
      const float4* pa = (const float4*)(u + ((size_t)b0*NI + i)*ND);
      const float4* pb = (const float4*)(u + ((size_t)b1*NI + i)*ND);
      #pragma unroll
      for (int q=0;q<4;++q){
        float4 xa = pa[q], xb = pb[q];
        u01[q*4+0] = v2f{xa.x, xb.x};
        u01[q*4+1] = v2f{xa.y, xb.y};
        u01[q*4+2] = v2f{xa.z, xb.z};
        u01[q*4+3] = v2f{xa.w, xb.w};
      }
    }
    v2f ss = {0.f, 0.f};
    #pragma unroll
    for (int d=0;d<16;++d){ v2f x = u01[d] + EPSF; ss += x*x; }
    const v2f av = {sqrtf(ss.x), sqrtf(ss.y)};

    // V for this lane's o, both batches packed (wide LDS reads)
    v2f V[16];
    #pragma unroll
    for (int e=0;e<16;++e){ float b = bs[e] + EPSF; V[e] = v2f{b, b}; }
    const float* row = &buf[p*BUFSZ + lane*RSTRIDE];
    #pragma unroll
    for (int e=0;e<16;++e){
      #pragma unroll
      for (int dq=0; dq<4; ++dq){
        const float4 wv = *(const float4*)(row + e*16 + dq*4);
        const int d = dq*4;
        V[e] += wv.x*u01[d+0];
        V[e] += wv.y*u01[d+1];
        V[e] += wv.z*u01[d+2];
        V[e] += wv.w*u01[d+3];
      }
    }

    v2f wg;
    if (ESTEP){
      v2f la = {0.f, 0.f};
      #pragma unroll
      for (int e=0;e<16;++e){ v2f df = V[e]-mr[e]; la += df*df*ir[e]; }
      v2f ap = c01 * v2f{__expf(-la.x), __expf(-la.y)};
      float q0 = ap.x, q1 = ap.y;
      #pragma unroll
      for (int off=32; off; off>>=1){
        q0 += __shfl_xor(q0, off);
        q1 += __shfl_xor(q1, off);
      }
      wg = v2f{ap.x/(q0 + EPSF)*av.x, ap.y/(q1 + EPSF)*av.y};
    } else {
      wg = av;                        // uniform rr: 1/64 applied in k_mred
    }
    wsum += wg;
    #pragma unroll
    for (int e=0;e<16;++e){
      v2f tv = wg*V[e]; S1[e]+=tv; S2[e]+=tv*V[e];
    }
    p ^= 1;
  }

  // store partials: each wave owns distinct b -> no cross-wave reduction
  const size_t ba = (((size_t)b0*CH + c)*NO + lane);
  const size_t bb = (((size_t)b1*CH + c)*NO + lane);
  #pragma unroll
  for (int e=0;e<16;++e){
    S1p[ba*ND+e]=S1[e].x; S2p[ba*ND+e]=S2[e].x;
    S1p[bb*ND+e]=S1[e].y; S2p[bb*ND+e]=S2[e].y;
  }
  Wsp[ba] = wsum.x; Wsp[bb] = wsum.y;  // m-pass: sum a_i; e-pass: sum rr*a
}

// ---------------- chunk-parallel partial reduction (shared by both) ---------
// block = 128 threads, one (b,o) per block; thread tc owns chunks tc, tc+128...
// then LDS tree-reduce 128 rows of 33 values. Result in red[0][0..32].
__device__ __forceinline__ void reduce_partials(
    const float* __restrict__ S1p, const float* __restrict__ S2p,
    const float* __restrict__ Wsp, const int CH, const int b, const int o,
    float (*red)[34])
{
  const int tc = threadIdx.x;
  float s1[16], s2[16]; float wv = 0.f;
  #pragma unroll
  for (int e=0;e<16;++e){ s1[e]=0.f; s2[e]=0.f; }
  for (int c = tc; c < CH; c += 128){
    const size_t base = ((((size_t)b*CH)+c)*NO + o)*ND;
    #pragma unroll
    for (int e=0;e<16;++e){ s1[e] += S1p[base+e]; s2[e] += S2p[base+e]; }
    wv += Wsp[(((size_t)b*CH)+c)*NO + o];
  }
  #pragma unroll
  for (int e=0;e<16;++e){ red[tc][e] = s1[e]; red[tc][16+e] = s2[e]; }
  red[tc][32] = wv;
  __syncthreads();
  #pragma unroll
  for (int s = 64; s >= 1; s >>= 1){
    if (tc < s){
      #pragma unroll
      for (int e=0;e<33;++e) red[tc][e] += red[tc+s][e];
    }
    __syncthreads();
  }
}

// ---------------- reduce m-step partials -> mean0,i2v0,c0 -------------------
__global__ __launch_bounds__(128) void k_mred(
    const float* __restrict__ beta_a, const float* __restrict__ beta_u,
    const float* __restrict__ S1p, const float* __restrict__ S2p,
    const float* __restrict__ Wsp, const int CH,
    float* __restrict__ mean0, float* __restrict__ i2v0, float* __restrict__ c0)
{
  const int bo = blockIdx.x;
  const int b = bo >> 6, o = bo & 63;
  const int t = threadIdx.x;
  __shared__ float red[128][34];
  __shared__ float ct_s[16], vt_s[16];
  reduce_partials(S1p, S2p, Wsp, CH, b, o, red);
  const float rrsum = red[0][32] * (1.f/64.f);
  if (t < 16){
    float T1 = red[0][t]   * (1.f/64.f);
    float T2 = red[0][16+t]* (1.f/64.f);
    float m  = T1/(rrsum + EPSF);
    float var = (T2 - 2.f*m*T1 + m*m*rrsum)/(rrsum + EPSF) + 1e-4f;
    const size_t mbase = ((size_t)b*NO + o)*ND;
    mean0[mbase+t] = m;
    i2v0[mbase+t]  = 1.f/(2.f*var + EPSF);
    ct_s[t] = beta_u[o] + __logf(var);
    vt_s[t] = var;
  }
  __syncthreads();
  if (t == 0){
    float cost = 0.f, prod = 1.f;
    #pragma unroll
    for (int e=0;e<16;++e){ cost += ct_s[e]; prod *= vt_s[e]; }
    cost *= rrsum;
    float x  = 5.0e-4f*(beta_a[o] - cost);   // inv_temp iter0 = 0.01*(1-0.95)
    float aj = 1.f/(1.f + __expf(-x));
    float p1 = sqrtf(6.2831853071795864f*prod + EPSF);
    c0[(size_t)b*NO + o] = aj/(p1 + EPSF);
  }
}

// ---------------- final: reduce e-partials, write output (fp32) -------------
__global__ __launch_bounds__(128) void k_final(
    const float* __restrict__ beta_a, const float* __restrict__ beta_u,
    const float* __restrict__ S1p, const float* __restrict__ S2p,
    const float* __restrict__ Wsp, const int CH,
    float* __restrict__ out)
{
  const int bo = blockIdx.x;
  const int b = bo >> 6, o = bo & 63;
  const int t = threadIdx.x;
  __shared__ float red[128][34];
  __shared__ float mean_s[16], ct_s[16], nt_s[16];
  __shared__ float scale_s;
  reduce_partials(S1p, S2p, Wsp, CH, b, o, red);
  const float Wsum = red[0][32];
  if (t < 16){
    float S1 = red[0][t], S2 = red[0][16+t];
    float m = S1/(Wsum + EPSF);
    float var = (S2 - 2.f*m*S1 + m*m*Wsum)/(Wsum + EPSF) + 1e-4f;
    mean_s[t] = m;
    ct_s[t] = beta_u[o] + __logf(var);
    float me = m + EPSF;
    nt_s[t] = me*me;
  }
  __syncthreads();
  if (t == 0){
    float cost=0.f, nrm=0.f;
    #pragma unroll
    for (int e=0;e<16;++e){ cost += ct_s[e]; nrm += nt_s[e]; }
    cost *= Wsum;
    float x = 9.75e-4f*(beta_a[o] - cost);  // inv_temp iter1 = 0.01*(1-0.95^2)
    float aj = 1.f/(1.f + __expf(-x));
    scale_s = aj/(sqrtf(nrm) + EPSF);
  }
  __syncthreads();
  if (t < 16){
    out[(size_t)bo*ND + t] = scale_s*mean_s[t];   // fp32 store
  }
}

// ---------------- host ------------------------------------------------------
extern "C" void kernel_launch(void* const* d_in, const int* in_sizes, int n_in,
                              void* d_out, int out_size, void* d_ws, size_t ws_size,
                              hipStream_t stream)
{
  const float* u      = (const float*)d_in[0];
  const float* W      = (const float*)d_in[1];
  const float* beta_a = (const float*)d_in[2];
  const float* beta_u = (const float*)d_in[3];
  const float* bias   = (const float*)d_in[4];
  float* ws  = (float*)d_ws;
  float* out = (float*)d_out;

  const size_t base_f = 2u*NB*NO*ND + NB*NO;                  // 135,168 floats
  auto need = [&](size_t ch){
    return (base_f + 2u*(size_t)NB*ch*NO*ND + (size_t)NB*ch*NO)*4;
  };
  int CH; int mode;   // 2 = 1024-thr 16-wave dbuf; 1 = R9 512-thr; 0 = R8 256-thr
  if      (ws_size >= need(128)){ CH = 128; mode = 2; }
  else if (ws_size >= need(64)) { CH = 64;  mode = 1; }
  else                          { CH = 32;  mode = 0; }

  float* mean0= ws;
  float* i2v0 = mean0 + (size_t)NB*NO*ND;
  float* c0   = i2v0 + (size_t)NB*NO*ND;
  float* S1p  = c0   + (size_t)NB*NO;
  float* S2p  = S1p  + (size_t)NB*CH*NO*ND;
  float* Wsp  = S2p  + (size_t)NB*CH*NO*ND;

  if (mode == 2){
    const int GRID = (NB/32)*CH;   // 256 blocks = 1/CU, 16 waves = 4/SIMD
    k_heavy<16,1,false><<<GRID, 1024, 0, stream>>>(u, W, bias,
        nullptr, nullptr, nullptr, S1p, S2p, Wsp, CH);
    k_mred<<<NB*NO, 128, 0, stream>>>(beta_a, beta_u, S1p, S2p, Wsp, CH,
                                      mean0, i2v0, c0);
    k_heavy<16,1,true><<<GRID, 1024, 0, stream>>>(u, W, bias,
        mean0, i2v0, c0, S1p, S2p, Wsp, CH);
  } else if (mode == 1){
    const int GRID = (NB/16)*CH;   // 256: proven R9 shape
    k_heavy<8,2,false><<<GRID, 512, 0, stream>>>(u, W, bias,
        nullptr, nullptr, nullptr, S1p, S2p, Wsp, CH);
    k_mred<<<NB*NO, 128, 0, stream>>>(beta_a, beta_u, S1p, S2p, Wsp, CH,
                                      mean0, i2v0, c0);
    k_heavy<8,2,true><<<GRID, 512, 0, stream>>>(u, W, bias,
        mean0, i2v0, c0, S1p, S2p, Wsp, CH);
  } else {
    const int GRID = (NB/8)*CH;    // 256: proven R8 shape
    k_heavy<4,2,false><<<GRID, 256, 0, stream>>>(u, W, bias,
        nullptr, nullptr, nullptr, S1p, S2p, Wsp, CH);
    k_mred<<<NB*NO, 128, 0, stream>>>(beta_a, beta_u, S1p, S2p, Wsp, CH,
                                      mean0, i2v0, c0);
    k_heavy<4,2,true><<<GRID, 256, 0, stream>>>(u, W, bias,
        mean0, i2v0, c0, S1p, S2p, Wsp, CH);
  }
  k_final<<<NB*NO, 128, 0, stream>>>(beta_a, beta_u, S1p, S2p, Wsp, CH, out);
}

// Round 14
// 462.955 us; speedup vs baseline: 1.3061x; 1.3061x over previous
//
#include <hip/hip_runtime.h>

#define EPSF 1e-8f

constexpr int NB = 64;   // batch
constexpr int NO = 64;   // out capsules
constexpr int NI = 1152; // in capsules
constexpr int ND = 16;   // pose dims

constexpr int RSTRIDE = 260;            // 256 floats + 4 pad (16B-aligned rows)
constexpr int BUFSZ   = 64 * RSTRIDE;   // one W-tile: 64 o-rows (66,560 B)

typedef float v2f __attribute__((ext_vector_type(2)));

// fp32 row loader ------------------------------------------------------------
__device__ __forceinline__ void loadrow16f(const float* __restrict__ base,
                                           size_t elem, float* f){
  const float4* p = (const float4*)(base + elem);
  float4 x0=p[0], x1=p[1], x2=p[2], x3=p[3];
  f[0]=x0.x; f[1]=x0.y; f[2]=x0.z; f[3]=x0.w;
  f[4]=x1.x; f[5]=x1.y; f[6]=x1.z; f[7]=x1.w;
  f[8]=x2.x; f[9]=x2.y; f[10]=x2.z; f[11]=x2.w;
  f[12]=x3.x; f[13]=x3.y; f[14]=x3.z; f[15]=x3.w;
}

// async global->LDS, 16 B per lane; lds dst is wave-uniform base + lane*16
__device__ __forceinline__ void gl_lds16(const float* g, float* l){
  __builtin_amdgcn_global_load_lds(
      (const __attribute__((address_space(1))) unsigned int*)g,
      (__attribute__((address_space(3))) unsigned int*)l,
      16, 0, 0);
}

// ---------------- heavy kernel --------------------------------------------
// PROVEN SHAPE (R9/R11: 131-146us): 512 thr = 8 waves, dbuf 133KB -> 1
// block/CU, 2 waves/SIMD, CH=64 (grid 256, CI=18). bid = bg*CH + c keeps
// same-c blocks on one XCD (W slice L2-local). Wave w owns b0=bg*16+2w, b1,
// packed in float2 lanes (v_pk_fma). Per i: W[:,i,:,:] DMA'd to LDS rows
// [o][256] stride 260; lane=o reads via ds_read_b128 (0 conflicts measured).
// NEW vs R9: (512,1) bound (cap>=212 per R7; LDS caps blocks anyway),
// u-prefetch for i+1 during compute of i, m-pass streams V (no V array).
// VGPR ALLOCATOR (measured R9-R13): (256,1)->212  (512,2)->128  (512,4)->64
// (1024,*)->64 ALWAYS. >=1024-thr blocks spill this body. Keep blocks <=512.
template<int NW, bool ESTEP>
__global__ __launch_bounds__(NW*64, 1) void k_heavy(
    const float* __restrict__ u, const float* __restrict__ W,
    const float* __restrict__ bias,
    const float* __restrict__ mean0, const float* __restrict__ i2v0,
    const float* __restrict__ c0,
    float* __restrict__ S1p, float* __restrict__ S2p, float* __restrict__ Wsp,
    const int CH)
{
  const int CI = NI / CH;
  constexpr int ROWS = 64 / NW;
  const int bid = blockIdx.x;
  const int bg = bid / CH, c = bid % CH;
  const int t = threadIdx.x, lane = t & 63, w = t >> 6;
  const int b0 = bg*(2*NW) + 2*w, b1 = b0 + 1;
  const int i0 = c*CI;

  __shared__ float buf[2*BUFSZ];   // 133,120 B double buffer

  // per-lane (=o) constants
  float bs[16]; loadrow16f(bias, (size_t)lane*ND, bs);
  v2f mr[16], ir[16]; v2f c01 = {0.f, 0.f};
  if (ESTEP){
    const size_t m0 = ((size_t)b0*NO + lane)*ND;
    const size_t m1 = ((size_t)b1*NO + lane)*ND;
    #pragma unroll
    for (int e=0;e<16;++e){
      mr[e] = v2f{mean0[m0+e], mean0[m1+e]};
      ir[e] = v2f{i2v0[m0+e], i2v0[m1+e]};
    }
    c01 = v2f{c0[(size_t)b0*NO + lane], c0[(size_t)b1*NO + lane]};
  }

  v2f S1[16], S2[16]; v2f wsum = {0.f, 0.f};
  #pragma unroll
  for (int e=0;e<16;++e){ S1[e]=v2f{0.f,0.f}; S2[e]=v2f{0.f,0.f}; }

  // stage W tile for column i into buffer p: wave w covers ROWS o-rows
  auto stage = [&](int p, int i){
    const float* gbase = W + (size_t)i*256 + (size_t)lane*4;
    float* lbase = &buf[p*BUFSZ];
    #pragma unroll
    for (int r=0;r<ROWS;++r){
      const int o = w*ROWS + r;
      gl_lds16(gbase + (size_t)o*NI*256, lbase + o*RSTRIDE);
    }
  };

  // u row pair loader (wave-uniform addresses -> broadcast)
  auto loadU = [&](int i, v2f* dst){
    const float4* pa = (const float4*)(u + ((size_t)b0*NI + i)*ND);
    const float4* pb = (const float4*)(u + ((size_t)b1*NI + i)*ND);
    #pragma unroll
    for (int q=0;q<4;++q){
      float4 xa = pa[q], xb = pb[q];
      dst[q*4+0] = v2f{xa.x, xb.x};
      dst[q*4+1] = v2f{xa.y, xb.y};
      dst[q*4+2] = v2f{xa.z, xb.z};
      dst[q*4+3] = v2f{xa.w, xb.w};
    }
  };

  int p = 0;
  stage(0, i0);
  v2f u01[16];
  loadU(i0, u01);                     // prefetched u for ii=0

  for (int ii=0; ii<CI; ++ii){
    const int i = i0 + ii;
    __syncthreads();                  // drains tile-p DMA; gates buffer reuse
    if (ii+1 < CI) stage(p^1, i+1);   // async, overlaps compute below

    v2f un[16];
    if (ii+1 < CI) loadU(i+1, un);    // prefetch next u during this compute

    v2f ss = {0.f, 0.f};
    #pragma unroll
    for (int d=0;d<16;++d){ v2f x = u01[d] + EPSF; ss += x*x; }
    const v2f av = {sqrtf(ss.x), sqrtf(ss.y)};

    const float* row = &buf[p*BUFSZ + lane*RSTRIDE];

    if (ESTEP){
      // V must persist across e for softmax -> V array
      v2f V[16];
      #pragma unroll
      for (int e=0;e<16;++e){ float b = bs[e] + EPSF; V[e] = v2f{b, b}; }
      #pragma unroll
      for (int e=0;e<16;++e){
        #pragma unroll
        for (int dq=0; dq<4; ++dq){
          const float4 wv = *(const float4*)(row + e*16 + dq*4);
          const int d = dq*4;
          V[e] += wv.x*u01[d+0];
          V[e] += wv.y*u01[d+1];
          V[e] += wv.z*u01[d+2];
          V[e] += wv.w*u01[d+3];
        }
      }
      v2f la = {0.f, 0.f};
      #pragma unroll
      for (int e=0;e<16;++e){ v2f df = V[e]-mr[e]; la += df*df*ir[e]; }
      v2f ap = c01 * v2f{__expf(-la.x), __expf(-la.y)};
      float q0 = ap.x, q1 = ap.y;
      #pragma unroll
      for (int off=32; off; off>>=1){
        q0 += __shfl_xor(q0, off);
        q1 += __shfl_xor(q1, off);
      }
      v2f wg = v2f{ap.x/(q0 + EPSF)*av.x, ap.y/(q1 + EPSF)*av.y};
      wsum += wg;
      #pragma unroll
      for (int e=0;e<16;++e){
        v2f tv = wg*V[e]; S1[e]+=tv; S2[e]+=tv*V[e];
      }
    } else {
      // m-pass: wg = a_i known BEFORE V -> stream V, no V array
      const v2f wg = av;
      wsum += wg;
      #pragma unroll
      for (int e=0;e<16;++e){
        v2f V = v2f{bs[e]+EPSF, bs[e]+EPSF};
        #pragma unroll
        for (int dq=0; dq<4; ++dq){
          const float4 wv = *(const float4*)(row + e*16 + dq*4);
          const int d = dq*4;
          V += wv.x*u01[d+0];
          V += wv.y*u01[d+1];
          V += wv.z*u01[d+2];
          V += wv.w*u01[d+3];
        }
        v2f tv = wg*V; S1[e]+=tv; S2[e]+=tv*V;
      }
    }

    if (ii+1 < CI){
      #pragma unroll
      for (int d=0;d<16;++d) u01[d] = un[d];
    }
    p ^= 1;
  }

  // store partials: each wave owns distinct b -> no cross-wave reduction
  const size_t ba = (((size_t)b0*CH + c)*NO + lane);
  const size_t bb = (((size_t)b1*CH + c)*NO + lane);
  #pragma unroll
  for (int e=0;e<16;++e){
    S1p[ba*ND+e]=S1[e].x; S2p[ba*ND+e]=S2[e].x;
    S1p[bb*ND+e]=S1[e].y; S2p[bb*ND+e]=S2[e].y;
  }
  Wsp[ba] = wsum.x; Wsp[bb] = wsum.y;  // m-pass: sum a_i; e-pass: sum rr*a
}

// ---------------- chunk-parallel partial reduction (shared) -----------------
// block = 128 threads, one (b,o) per block; thread tc owns chunks tc, tc+128..
// then LDS tree-reduce. Result in red[0][0..32]. (R12: reduces ~37us total)
__device__ __forceinline__ void reduce_partials(
    const float* __restrict__ S1p, const float* __restrict__ S2p,
    const float* __restrict__ Wsp, const int CH, const int b, const int o,
    float (*red)[34])
{
  const int tc = threadIdx.x;
  float s1[16], s2[16]; float wv = 0.f;
  #pragma unroll
  for (int e=0;e<16;++e){ s1[e]=0.f; s2[e]=0.f; }
  for (int c = tc; c < CH; c += 128){
    const size_t base = ((((size_t)b*CH)+c)*NO + o)*ND;
    #pragma unroll
    for (int e=0;e<16;++e){ s1[e] += S1p[base+e]; s2[e] += S2p[base+e]; }
    wv += Wsp[(((size_t)b*CH)+c)*NO + o];
  }
  #pragma unroll
  for (int e=0;e<16;++e){ red[tc][e] = s1[e]; red[tc][16+e] = s2[e]; }
  red[tc][32] = wv;
  __syncthreads();
  #pragma unroll
  for (int s = 64; s >= 1; s >>= 1){
    if (tc < s){
      #pragma unroll
      for (int e=0;e<33;++e) red[tc][e] += red[tc+s][e];
    }
    __syncthreads();
  }
}

// ---------------- reduce m-step partials -> mean0,i2v0,c0 -------------------
__global__ __launch_bounds__(128) void k_mred(
    const float* __restrict__ beta_a, const float* __restrict__ beta_u,
    const float* __restrict__ S1p, const float* __restrict__ S2p,
    const float* __restrict__ Wsp, const int CH,
    float* __restrict__ mean0, float* __restrict__ i2v0, float* __restrict__ c0)
{
  const int bo = blockIdx.x;
  const int b = bo >> 6, o = bo & 63;
  const int t = threadIdx.x;
  __shared__ float red[128][34];
  __shared__ float ct_s[16], vt_s[16];
  reduce_partials(S1p, S2p, Wsp, CH, b, o, red);
  const float rrsum = red[0][32] * (1.f/64.f);
  if (t < 16){
    float T1 = red[0][t]   * (1.f/64.f);
    float T2 = red[0][16+t]* (1.f/64.f);
    float m  = T1/(rrsum + EPSF);
    float var = (T2 - 2.f*m*T1 + m*m*rrsum)/(rrsum + EPSF) + 1e-4f;
    const size_t mbase = ((size_t)b*NO + o)*ND;
    mean0[mbase+t] = m;
    i2v0[mbase+t]  = 1.f/(2.f*var + EPSF);
    ct_s[t] = beta_u[o] + __logf(var);
    vt_s[t] = var;
  }
  __syncthreads();
  if (t == 0){
    float cost = 0.f, prod = 1.f;
    #pragma unroll
    for (int e=0;e<16;++e){ cost += ct_s[e]; prod *= vt_s[e]; }
    cost *= rrsum;
    float x  = 5.0e-4f*(beta_a[o] - cost);   // inv_temp iter0 = 0.01*(1-0.95)
    float aj = 1.f/(1.f + __expf(-x));
    float p1 = sqrtf(6.2831853071795864f*prod + EPSF);
    c0[(size_t)b*NO + o] = aj/(p1 + EPSF);
  }
}

// ---------------- final: reduce e-partials, write output (fp32) -------------
__global__ __launch_bounds__(128) void k_final(
    const float* __restrict__ beta_a, const float* __restrict__ beta_u,
    const float* __restrict__ S1p, const float* __restrict__ S2p,
    const float* __restrict__ Wsp, const int CH,
    float* __restrict__ out)
{
  const int bo = blockIdx.x;
  const int b = bo >> 6, o = bo & 63;
  const int t = threadIdx.x;
  __shared__ float red[128][34];
  __shared__ float mean_s[16], ct_s[16], nt_s[16];
  __shared__ float scale_s;
  reduce_partials(S1p, S2p, Wsp, CH, b, o, red);
  const float Wsum = red[0][32];
  if (t < 16){
    float S1 = red[0][t], S2 = red[0][16+t];
    float m = S1/(Wsum + EPSF);
    float var = (S2 - 2.f*m*S1 + m*m*Wsum)/(Wsum + EPSF) + 1e-4f;
    mean_s[t] = m;
    ct_s[t] = beta_u[o] + __logf(var);
    float me = m + EPSF;
    nt_s[t] = me*me;
  }
  __syncthreads();
  if (t == 0){
    float cost=0.f, nrm=0.f;
    #pragma unroll
    for (int e=0;e<16;++e){ cost += ct_s[e]; nrm += nt_s[e]; }
    cost *= Wsum;
    float x = 9.75e-4f*(beta_a[o] - cost);  // inv_temp iter1 = 0.01*(1-0.95^2)
    float aj = 1.f/(1.f + __expf(-x));
    scale_s = aj/(sqrtf(nrm) + EPSF);
  }
  __syncthreads();
  if (t < 16){
    out[(size_t)bo*ND + t] = scale_s*mean_s[t];   // fp32 store
  }
}

// ---------------- host ------------------------------------------------------
extern "C" void kernel_launch(void* const* d_in, const int* in_sizes, int n_in,
                              void* d_out, int out_size, void* d_ws, size_t ws_size,
                              hipStream_t stream)
{
  const float* u      = (const float*)d_in[0];
  const float* W      = (const float*)d_in[1];
  const float* beta_a = (const float*)d_in[2];
  const float* beta_u = (const float*)d_in[3];
  const float* bias   = (const float*)d_in[4];
  float* ws  = (float*)d_ws;
  float* out = (float*)d_out;

  const size_t base_f = 2u*NB*NO*ND + NB*NO;                  // 135,168 floats
  auto need = [&](size_t ch){
    return (base_f + 2u*(size_t)NB*ch*NO*ND + (size_t)NB*ch*NO)*4;
  };
  int CH; int mode;   // 1 = 512-thr dbuf (proven R9); 0 = 256-thr dbuf (R8)
  if      (ws_size >= need(64)) { CH = 64;  mode = 1; }
  else                          { CH = 32;  mode = 0; }

  float* mean0= ws;
  float* i2v0 = mean0 + (size_t)NB*NO*ND;
  float* c0   = i2v0 + (size_t)NB*NO*ND;
  float* S1p  = c0   + (size_t)NB*NO;
  float* S2p  = S1p  + (size_t)NB*CH*NO*ND;
  float* Wsp  = S2p  + (size_t)NB*CH*NO*ND;

  if (mode == 1){
    const int GRID = (NB/16)*CH;   // 256 blocks = 1/CU (LDS-capped)
    k_heavy<8,false><<<GRID, 512, 0, stream>>>(u, W, bias,
        nullptr, nullptr, nullptr, S1p, S2p, Wsp, CH);
    k_mred<<<NB*NO, 128, 0, stream>>>(beta_a, beta_u, S1p, S2p, Wsp, CH,
                                      mean0, i2v0, c0);
    k_heavy<8,true><<<GRID, 512, 0, stream>>>(u, W, bias,
        mean0, i2v0, c0, S1p, S2p, Wsp, CH);
  } else {
    const int GRID = (NB/8)*CH;    // 256: proven R8 shape
    k_heavy<4,false><<<GRID, 256, 0, stream>>>(u, W, bias,
        nullptr, nullptr, nullptr, S1p, S2p, Wsp, CH);
    k_mred<<<NB*NO, 128, 0, stream>>>(beta_a, beta_u, S1p, S2p, Wsp, CH,
                                      mean0, i2v0, c0);
    k_heavy<4,true><<<GRID, 256, 0, stream>>>(u, W, bias,
        mean0, i2v0, c0, S1p, S2p, Wsp, CH);
  }
  k_final<<<NB*NO, 128, 0, stream>>>(beta_a, beta_u, S1p, S2p, Wsp, CH, out);
}